// Round 10
// baseline (473.625 us; speedup 1.0000x reference)
//
// GINModel_15058155340592 — HIP implementation.
// Keep the identifier kernel symbol below: the harness uses it to map
// this source to its test (R1-R3 failed without it).
//
// JOURNAL (counter-driven):
//  R4: fused pool/fp8 into GEMM epilogue -> VGPR spill (WRITE 120MB, occ 13%).
//  R6: fused W1/W2 MLP kernel -> TWO weight sets co-resident (~300 VGPR demand)
//      -> 128 alloc + massive scratch (WRITE 420MB). LESSON: one reg-resident
//      weight set max; fusions must keep peak demand under 256 VGPR.
//  R7: verified baseline 410 us (R2 structure + k_c4 padx fusion).
//  R8: pool vectorized + layer-2 pool+clf merged -> 398 us.
//  R9: GEMM B-frag column permutation -> 4x u16x8 epilogue stores -> 371 us.
//  R10: agg + W1-GEMM fused (k_aggmm): z staged through 17.4KB LDS slab, ONE
//       weight set in regs (peak ~190 VGPR < 256) -> kills 51MB z round-trip
//       per layer x2. Failure signature to watch: WRITE >> 26MB => spill.
#include <hip/hip_runtime.h>

#define N_NODESC    100000
#define N_EDGESC    1600000
#define NUM_GRAPHSC 1024
#define IN_FEATC    7
#define HDIM        128
#define N_TENSORS   20

// bucketed CSR build: bucket = dst >> 8 (256 nodes per bucket)
#define NB       391            // ceil(100000/256)
#define CHUNK_A  6250           // edges per block in bucket passes (256 blocks)
#define NPADB    391            // ceil(100000/256) padx blocks in k_c4 tail

typedef short s16x8 __attribute__((ext_vector_type(8)));
typedef float f32x4 __attribute__((ext_vector_type(4)));
typedef unsigned short u16x8 __attribute__((ext_vector_type(8)));

#if defined(__has_builtin)
# if __has_builtin(__builtin_amdgcn_cvt_pk_f32_fp8) && __has_builtin(__builtin_amdgcn_cvt_pk_fp8_f32)
#  define USE_HW_FP8 1
# endif
#endif

__global__ void GINModel_15058155340592_kernel(/* identifier-preserving stub */) {
}

__device__ __forceinline__ float b2f(unsigned short u){
  union { unsigned int i; float f; } v;
  v.i = ((unsigned int)u) << 16;
  return v.f;
}
__device__ __forceinline__ unsigned short f2b(float f){
  union { float f; unsigned int i; } v;
  v.f = f;
  unsigned int x = v.i;
  return (unsigned short)((x + 0x7fffu + ((x >> 16) & 1u)) >> 16);
}

// fp8 e4m3fn helpers (values are post-relu >= 0; stored as h/8, clamp 448)
__device__ __forceinline__ unsigned char enc_fp8(float h){
  float x = fminf(h * 0.125f, 448.f);
#ifdef USE_HW_FP8
  int r = __builtin_amdgcn_cvt_pk_fp8_f32(x, x, 0, false);
  return (unsigned char)(r & 0xFF);
#else
  union { float f; unsigned int i; } u; u.f = x;
  unsigned b = u.i;
  b += 0x7FFFF + ((b >> 20) & 1);           // RTNE to 3 mantissa bits
  int e = (int)((b >> 23) & 0xFF) - 120;    // e4m3 biased exponent
  unsigned m = (b >> 20) & 7;
  if (e <= 0) return 0;                     // flush subnormal
  if (e > 15) return 0x7E;                  // saturate 448
  return (unsigned char)((e << 3) | m);
#endif
}

// accumulate 4 fp8 bytes (packed in u) into a[base..base+3]
__device__ __forceinline__ void acc_fp8x4(unsigned int u, float* a){
#ifdef USE_HW_FP8
  auto lo = __builtin_amdgcn_cvt_pk_f32_fp8((int)u, false);
  auto hi = __builtin_amdgcn_cvt_pk_f32_fp8((int)u, true);
  a[0] += lo[0]; a[1] += lo[1]; a[2] += hi[0]; a[3] += hi[1];
#else
  #pragma unroll
  for (int k = 0; k < 4; ++k){
    unsigned b = (u >> (k * 8)) & 0xFF;
    unsigned e = (b >> 3) & 0xF;
    unsigned m = b & 7;
    union { unsigned int i; float f; } w;
    w.i = ((e + 120) << 23) | (m << 20);
    float v = (e == 0) ? (float)m * 0.001953125f : w.f;
    a[k] += v;
  }
#endif
}

// accumulate 4 bf16 (uint2) into 4 floats
__device__ __forceinline__ void acc_bf4(uint2 v, float& a0, float& a1,
                                        float& a2, float& a3){
  union { unsigned int i; float f; } t;
  t.i = v.x << 16;          a0 += t.f;
  t.i = v.x & 0xffff0000u;  a1 += t.f;
  t.i = v.y << 16;          a2 += t.f;
  t.i = v.y & 0xffff0000u;  a3 += t.f;
}

// ---------------- dtype detect (+ zero bcnt) ----------------
__global__ void k_detect(const unsigned short* xb, int* flag, int* bcnt){
  __shared__ int sh[256];
  int t = threadIdx.x;
  for (int i = t; i < 512; i += 256) bcnt[i] = 0;
  int cnt = 0;
  for (int i = t; i < 512; i += 256){
    unsigned e = (xb[i] >> 7) & 0xFF;
    if (e >= 0x68 && e <= 0x85) ++cnt;
  }
  sh[t] = cnt;
  __syncthreads();
  for (int s = 128; s > 0; s >>= 1){
    if (t < s) sh[t] += sh[t + s];
    __syncthreads();
  }
  if (t == 0) *flag = (sh[0] >= 400) ? 1 : 0;   // 1 = bf16 inputs, 0 = f32
}

struct CvtDesc { const void* src; int n; int off; };
struct CvtTable { CvtDesc d[N_TENSORS]; int total; };

// ---------------- bucketed CSR build ----------------
__global__ void k_bhist(const int* dst, int* bcnt){
  __shared__ int h[NB];
  int tid = threadIdx.x;
  for (int i = tid; i < NB; i += 256) h[i] = 0;
  __syncthreads();
  int beg = blockIdx.x * CHUNK_A;
  int end = beg + CHUNK_A < N_EDGESC ? beg + CHUNK_A : N_EDGESC;
  for (int e = beg + tid; e < end; e += 256)
    atomicAdd(&h[dst[e] >> 8], 1);
  __syncthreads();
  for (int i = tid; i < NB; i += 256)
    if (h[i]) atomicAdd(&bcnt[i], h[i]);
}

// block 0: scan bucket counts. blocks 1..: graph-start detection (gstart).
__global__ void k_c2(const int* bcnt, int* bbase, int* bcursor, int* rowstart,
                     const int* batch, int* gs){
  if (blockIdx.x == 0){
    __shared__ int sh[512];
    int t = threadIdx.x;
    int v = (t < NB) ? bcnt[t] : 0;
    sh[t] = v;
    __syncthreads();
    for (int off = 1; off < 512; off <<= 1){
      int a = (t >= off) ? sh[t - off] : 0;
      __syncthreads();
      sh[t] += a;
      __syncthreads();
    }
    int excl = sh[t] - v;
    if (t < NB){ bbase[t] = excl; bcursor[t] = excl; }
    if (t == NB) bbase[NB] = sh[t];    // == N_EDGESC
    if (t == 0) rowstart[N_NODESC] = N_EDGESC;
  } else {
    int n = (blockIdx.x - 1) * 512 + threadIdx.x;
    if (n >= N_NODESC) return;
    int b = batch[n];
    if (n == 0){
      for (int g = 0; g <= b; ++g) gs[g] = 0;
    } else {
      int pb = batch[n - 1];
      if (pb != b){
        for (int g = pb + 1; g <= b; ++g) gs[g] = n;
      }
    }
    if (n == N_NODESC - 1){
      for (int g = b + 1; g <= NUM_GRAPHSC; ++g) gs[g] = N_NODESC;
    }
  }
}

__global__ void k_bscatter(const int* src, const int* dst, int* bcursor,
                           unsigned int* barr){
  __shared__ int lhist[NB];
  __shared__ int lbase[NB];
  int tid = threadIdx.x;
  for (int i = tid; i < NB; i += 256) lhist[i] = 0;
  __syncthreads();
  int beg = blockIdx.x * CHUNK_A;
  int end = beg + CHUNK_A < N_EDGESC ? beg + CHUNK_A : N_EDGESC;
  for (int e = beg + tid; e < end; e += 256)
    atomicAdd(&lhist[dst[e] >> 8], 1);
  __syncthreads();
  for (int b = tid; b < NB; b += 256){
    int c = lhist[b];
    lbase[b] = c ? atomicAdd(&bcursor[b], c) : 0;
  }
  __syncthreads();
  for (int i = tid; i < NB; i += 256) lhist[i] = 0;   // reuse as run cursor
  __syncthreads();
  for (int e = beg + tid; e < end; e += 256){
    int d = dst[e];
    int b = d >> 8;
    int ofs = atomicAdd(&lhist[b], 1);
    barr[lbase[b] + ofs] = ((unsigned)(d & 255) << 17) | (unsigned)src[e];
  }
}

// blocks 0..NB-1: per-bucket CSR finalize (csr holds src<<7).
// blocks NB..NB+ncvtb-1: param pool conversion.
// blocks NB+ncvtb..: pad x into [N][8] bf16 rows (x8, 16 B/row, f7 = 0).
__global__ void k_c4(const unsigned int* barr, const int* bbase,
                     int* rowstart, int* csr,
                     CvtTable T, unsigned short* pool, const int* flag,
                     int ncvtb, const void* xin, unsigned short* x8){
  if (blockIdx.x < NB){
    __shared__ int h[256];
    __shared__ int sc[256];
    __shared__ int cur[256];
    int tid = threadIdx.x;
    int b = blockIdx.x;
    int beg = bbase[b];
    int end = bbase[b + 1];
    int n0 = b << 8;
    h[tid] = 0;
    __syncthreads();
    for (int i = beg + tid; i < end; i += 256)
      atomicAdd(&h[barr[i] >> 17], 1);
    __syncthreads();
    int v = h[tid];
    sc[tid] = v;
    __syncthreads();
    for (int off = 1; off < 256; off <<= 1){
      int a = (tid >= off) ? sc[tid - off] : 0;
      __syncthreads();
      sc[tid] += a;
      __syncthreads();
    }
    int excl = sc[tid] - v;
    int node = n0 + tid;
    if (node < N_NODESC) rowstart[node] = beg + excl;
    cur[tid] = beg + excl;
    __syncthreads();
    for (int i = beg + tid; i < end; i += 256){
      unsigned int e = barr[i];
      int local = e >> 17;
      int slot = atomicAdd(&cur[local], 1);
      csr[slot] = (int)(e & 0x1FFFF) << 7;
    }
  } else {
    int bx = blockIdx.x - NB;
    if (bx < ncvtb){
      int i = bx * 256 + threadIdx.x;
      if (i >= T.total) return;
      int isbf = *flag;
      for (int j = 0; j < N_TENSORS; ++j){
        int o = T.d[j].off;
        if (i >= o && i < o + T.d[j].n){
          int k = i - o;
          if (isbf) pool[i] = ((const unsigned short*)T.d[j].src)[k];
          else      pool[i] = f2b(((const float*)T.d[j].src)[k]);
          return;
        }
      }
    } else {
      int n = (bx - ncvtb) * 256 + threadIdx.x;
      if (n >= N_NODESC) return;
      u16x8 o;
      if (*flag){
        const unsigned short* s = (const unsigned short*)xin + (size_t)n * IN_FEATC;
        #pragma unroll
        for (int j = 0; j < IN_FEATC; ++j) o[j] = s[j];
      } else {
        const float* s = (const float*)xin + (size_t)n * IN_FEATC;
        #pragma unroll
        for (int j = 0; j < IN_FEATC; ++j) o[j] = f2b(s[j]);
      }
      o[7] = 0;
      *(u16x8*)(x8 + (size_t)n * 8) = o;
    }
  }
}

// ---------------- layer 0: fused aggregate + [7]->[128] matmul ----------------
// 2 lanes per node (32 nodes/wave, 128 nodes/block). Each lane privately
// accumulates its 8-B half of the padded 16-B x8 row per edge (uint2 gather,
// 4-deep unrolled). z staged via 4 KB LDS; matmul keeps the 7x2 weight slice
// in registers; stores write coalesced 256-B rows.
__global__ __launch_bounds__(256)
void k_l0(const unsigned short* x8, const int* rs, const int* csr,
          const unsigned short* w1, const unsigned short* b1,
          unsigned short* t){
  __shared__ __align__(16) float sz[128 * 8];
  int tid  = threadIdx.x;
  int lane = tid & 63;
  int wave = tid >> 6;
  int p    = tid & 1;            // half-row selector (f0-3 / f4-7)
  int bn   = tid >> 1;           // node slot in block 0..127
  int n    = blockIdx.x * 128 + bn;

  // per-lane weight slice: cols c0, c0+1 for k = 0..6 (+ bias pair)
  int c0 = lane * 2;
  float wa[IN_FEATC], wb[IN_FEATC];
  #pragma unroll
  for (int k = 0; k < IN_FEATC; ++k){
    unsigned int u = *(const unsigned int*)(w1 + k * HDIM + c0);
    union { unsigned int i; float f; } lo, hi;
    lo.i = u << 16; hi.i = u & 0xffff0000u;
    wa[k] = lo.f; wb[k] = hi.f;
  }
  unsigned int ub = *(const unsigned int*)(b1 + c0);
  union { unsigned int i; float f; } blo, bhi;
  blo.i = ub << 16; bhi.i = ub & 0xffff0000u;
  float bv0 = blo.f, bv1 = bhi.f;

  // aggregation: gather neighbor half-rows (csr holds src<<7 -> byte off = csr>>3)
  float a0 = 0.f, a1 = 0.f, a2 = 0.f, a3 = 0.f;
  int beg = 0, end = 0;
  if (n < N_NODESC){ beg = rs[n]; end = rs[n + 1]; }
  const unsigned char* xb = (const unsigned char*)x8 + p * 8;
  int i = beg;
  for (; i + 4 <= end; i += 4){
    int o0 = csr[i + 0];
    int o1 = csr[i + 1];
    int o2 = csr[i + 2];
    int o3 = csr[i + 3];
    uint2 v0 = *(const uint2*)(xb + (o0 >> 3));
    uint2 v1 = *(const uint2*)(xb + (o1 >> 3));
    uint2 v2 = *(const uint2*)(xb + (o2 >> 3));
    uint2 v3 = *(const uint2*)(xb + (o3 >> 3));
    acc_bf4(v0, a0, a1, a2, a3);
    acc_bf4(v1, a0, a1, a2, a3);
    acc_bf4(v2, a0, a1, a2, a3);
    acc_bf4(v3, a0, a1, a2, a3);
  }
  for (; i < end; ++i){
    uint2 v = *(const uint2*)(xb + (csr[i] >> 3));
    acc_bf4(v, a0, a1, a2, a3);
  }
  if (n < N_NODESC){  // self term (eps=0)
    uint2 v = *(const uint2*)((const unsigned char*)x8 + (size_t)n * 16 + p * 8);
    acc_bf4(v, a0, a1, a2, a3);
  }
  *(f32x4*)&sz[bn * 8 + p * 4] = f32x4{a0, a1, a2, a3};
  __syncthreads();

  // matmul: wave iterates its 32 nodes; z broadcast from LDS, weights in regs
  int j0 = wave * 32;
  for (int j = 0; j < 32; ++j){
    int no = blockIdx.x * 128 + j0 + j;
    f32x4 z0 = *(const f32x4*)&sz[(j0 + j) * 8];
    f32x4 z1 = *(const f32x4*)&sz[(j0 + j) * 8 + 4];
    float acc0 = bv0, acc1 = bv1;
    acc0 += z0[0] * wa[0]; acc1 += z0[0] * wb[0];
    acc0 += z0[1] * wa[1]; acc1 += z0[1] * wb[1];
    acc0 += z0[2] * wa[2]; acc1 += z0[2] * wb[2];
    acc0 += z0[3] * wa[3]; acc1 += z0[3] * wb[3];
    acc0 += z1[0] * wa[4]; acc1 += z1[0] * wb[4];
    acc0 += z1[1] * wa[5]; acc1 += z1[1] * wb[5];
    acc0 += z1[2] * wa[6]; acc1 += z1[2] * wb[6];
    if (no < N_NODESC){
      unsigned int pk = ((unsigned)f2b(fmaxf(acc1, 0.f)) << 16)
                      | (unsigned)f2b(fmaxf(acc0, 0.f));
      *(unsigned int*)(t + ((size_t)no << 7) + c0) = pk;
    }
  }
}

// ---------------- MFMA GEMM: [N,128]@[128,128]+bias, relu, bf16 ----------------
// R9 column-permuted B-fragments; coalesced u16x8 epilogue.
__global__ __launch_bounds__(256, 2)
void k_gemm128m(const unsigned short* A, const unsigned short* W,
                const unsigned short* bias, unsigned short* C, int ntiles)
{
  int wave = threadIdx.x >> 6;
  int lane = threadIdx.x & 63;
  int quad = lane >> 4;
  int l16  = lane & 15;

  union BU { s16x8 v; unsigned short s[8]; };
  BU bf[4][8];
  #pragma unroll
  for (int ks = 0; ks < 4; ++ks)
    #pragma unroll
    for (int ct = 0; ct < 8; ++ct){
      int c = l16 * 8 + ct;               // permuted column assignment
      #pragma unroll
      for (int j = 0; j < 8; ++j)
        bf[ks][ct].s[j] = W[(ks * 32 + quad * 8 + j) * HDIM + c];
    }

  float bv[8];
  #pragma unroll
  for (int ct = 0; ct < 8; ++ct) bv[ct] = b2f(bias[l16 * 8 + ct]);

  for (int tile = blockIdx.x; tile < ntiles; tile += gridDim.x){
    int r = tile * 64 + wave * 16 + l16;
    BU af[4];
    if (r < N_NODESC){
      const unsigned short* arow = A + (size_t)r * HDIM;
      #pragma unroll
      for (int ks = 0; ks < 4; ++ks)
        af[ks].v = *reinterpret_cast<const s16x8*>(arow + ks * 32 + quad * 8);
    } else {
      #pragma unroll
      for (int ks = 0; ks < 4; ++ks)
        #pragma unroll
        for (int j = 0; j < 8; ++j) af[ks].s[j] = 0;
    }
    f32x4 acc[8];
    #pragma unroll
    for (int ct = 0; ct < 8; ++ct) acc[ct] = f32x4{0.f, 0.f, 0.f, 0.f};
    #pragma unroll
    for (int ks = 0; ks < 4; ++ks)
      #pragma unroll
      for (int ct = 0; ct < 8; ++ct)
        acc[ct] = __builtin_amdgcn_mfma_f32_16x16x32_bf16(af[ks].v, bf[ks][ct].v,
                                                          acc[ct], 0, 0, 0);

    int orow = tile * 64 + wave * 16 + quad * 4;  // C/D row = quad*4 + reg
    #pragma unroll
    for (int rr = 0; rr < 4; ++rr){
      int row = orow + rr;
      if (row < N_NODESC){
        u16x8 o;
        #pragma unroll
        for (int ct = 0; ct < 8; ++ct)
          o[ct] = f2b(fmaxf(acc[ct][rr] + bv[ct], 0.f));
        *(u16x8*)(C + ((size_t)row << 7) + l16 * 8) = o;
      }
    }
  }
}

// ---------------- fused CSR aggregate + W1 GEMM (R10) -----------------------
// One 64-row tile per block (grid 1563). Wave w owns rows w*16..w*16+15:
//  phase 1 (agg): 4 slots (quad) x 4 passes gather each node's fp8 row from
//    t8 (16 lanes x 8 B = one 128-B line per edge), add bf16 self term, and
//    write z as bf16 into a [64][136] LDS slab (same f2b rounding as the old
//    z store -> numerically identical to the unfused pipeline).
//  phase 2 (GEMM): byte-identical R9 MFMA + coalesced epilogue, with A-frags
//    read from the slab (row stride 272 B -> ds_read_b128 at 2-way conflicts
//    = free per G4).
// Register budget (R4/R6 lesson): ONE weight set (128 VGPR) + agg state (~35)
// + acc/af (~48, agg regs dead) => peak ~190 < 256 cap of launch_bounds(256,2).
__global__ __launch_bounds__(256, 2)
void k_aggmm(const unsigned short* hin, const unsigned char* t8,
             const int* rs, const int* csr,
             const unsigned short* W, const unsigned short* bias,
             unsigned short* C)
{
  __shared__ __align__(16) unsigned short z[64 * 136];
  int wave = threadIdx.x >> 6;
  int lane = threadIdx.x & 63;
  int quad = lane >> 4;
  int l16  = lane & 15;
  int tile = blockIdx.x;

  union BU { s16x8 v; unsigned short s[8]; };
  BU bf[4][8];
  #pragma unroll
  for (int ks = 0; ks < 4; ++ks)
    #pragma unroll
    for (int ct = 0; ct < 8; ++ct){
      int c = l16 * 8 + ct;               // permuted column assignment (R9)
      #pragma unroll
      for (int j = 0; j < 8; ++j)
        bf[ks][ct].s[j] = W[(ks * 32 + quad * 8 + j) * HDIM + c];
    }
  float bv[8];
  #pragma unroll
  for (int ct = 0; ct < 8; ++ct) bv[ct] = b2f(bias[l16 * 8 + ct]);

  // phase 1: aggregation into the slab (slot = quad owns one node per pass)
  const unsigned char* hb8 = t8 + l16 * 8;
  for (int it = 0; it < 4; ++it){
    int row = wave * 16 + quad * 4 + it;
    int n = tile * 64 + row;
    u16x8 o;
    if (n < N_NODESC){
      int beg = rs[n];
      int end = rs[n + 1];
      float a[8] = {0.f, 0.f, 0.f, 0.f, 0.f, 0.f, 0.f, 0.f};
      int i = beg;
      for (; i + 4 <= end; i += 4){
        int o0 = csr[i + 0];
        int o1 = csr[i + 1];
        int o2 = csr[i + 2];
        int o3 = csr[i + 3];
        uint2 v0 = *(const uint2*)(hb8 + o0);
        uint2 v1 = *(const uint2*)(hb8 + o1);
        uint2 v2 = *(const uint2*)(hb8 + o2);
        uint2 v3 = *(const uint2*)(hb8 + o3);
        acc_fp8x4(v0.x, a); acc_fp8x4(v0.y, a + 4);
        acc_fp8x4(v1.x, a); acc_fp8x4(v1.y, a + 4);
        acc_fp8x4(v2.x, a); acc_fp8x4(v2.y, a + 4);
        acc_fp8x4(v3.x, a); acc_fp8x4(v3.y, a + 4);
      }
      for (; i < end; ++i){
        uint2 v = *(const uint2*)(hb8 + csr[i]);
        acc_fp8x4(v.x, a); acc_fp8x4(v.y, a + 4);
      }
      u16x8 vs = *(const u16x8*)(hin + ((size_t)n << 7) + l16 * 8);
      #pragma unroll
      for (int j = 0; j < 8; ++j) o[j] = f2b(a[j] * 8.f + b2f(vs[j]));
    } else {
      #pragma unroll
      for (int j = 0; j < 8; ++j) o[j] = 0;
    }
    *(u16x8*)&z[row * 136 + l16 * 8] = o;
  }
  __syncthreads();

  // phase 2: MFMA GEMM, A-frags from the slab
  BU af[4];
  #pragma unroll
  for (int ks = 0; ks < 4; ++ks)
    af[ks].v = *reinterpret_cast<const s16x8*>(
        &z[(wave * 16 + l16) * 136 + ks * 32 + quad * 8]);
  f32x4 acc[8];
  #pragma unroll
  for (int ct = 0; ct < 8; ++ct) acc[ct] = f32x4{0.f, 0.f, 0.f, 0.f};
  #pragma unroll
  for (int ks = 0; ks < 4; ++ks)
    #pragma unroll
    for (int ct = 0; ct < 8; ++ct)
      acc[ct] = __builtin_amdgcn_mfma_f32_16x16x32_bf16(af[ks].v, bf[ks][ct].v,
                                                        acc[ct], 0, 0, 0);

  int orow = tile * 64 + wave * 16 + quad * 4;
  #pragma unroll
  for (int rr = 0; rr < 4; ++rr){
    int row = orow + rr;
    if (row < N_NODESC){
      u16x8 o;
      #pragma unroll
      for (int ct = 0; ct < 8; ++ct)
        o[ct] = f2b(fmaxf(acc[ct][rr] + bv[ct], 0.f));
      *(u16x8*)(C + ((size_t)row << 7) + l16 * 8) = o;
    }
  }
}

// ---------------- pooling v2: u16x8 loads, packed fp8, LDS reduce -----------
__global__ void k_poolA(const unsigned short* __restrict__ h,
                        const int* __restrict__ gs,
                        float* __restrict__ pooled, int coloff,
                        unsigned char* __restrict__ c8){
  __shared__ float red16[16][136];
  int g = blockIdx.x;
  int t = threadIdx.x;
  int r = t >> 4;
  int c = t & 15;
  int s = gs[g];
  int e = gs[g + 1];
  float pa[8] = {0.f, 0.f, 0.f, 0.f, 0.f, 0.f, 0.f, 0.f};
  if (c8){
    for (int n = s + r; n < e; n += 16){
      u16x8 hv = *(const u16x8*)(h + ((size_t)n << 7) + c * 8);
      unsigned int w0 = (unsigned)enc_fp8(b2f(hv[0]))
                      | ((unsigned)enc_fp8(b2f(hv[1])) << 8)
                      | ((unsigned)enc_fp8(b2f(hv[2])) << 16)
                      | ((unsigned)enc_fp8(b2f(hv[3])) << 24);
      unsigned int w1 = (unsigned)enc_fp8(b2f(hv[4]))
                      | ((unsigned)enc_fp8(b2f(hv[5])) << 8)
                      | ((unsigned)enc_fp8(b2f(hv[6])) << 16)
                      | ((unsigned)enc_fp8(b2f(hv[7])) << 24);
      *(uint2*)(c8 + ((size_t)n << 7) + c * 8) = uint2{w0, w1};
      #pragma unroll
      for (int j = 0; j < 8; ++j) pa[j] += b2f(hv[j]);
    }
  } else {
    for (int n = s + r; n < e; n += 16){
      u16x8 hv = *(const u16x8*)(h + ((size_t)n << 7) + c * 8);
      #pragma unroll
      for (int j = 0; j < 8; ++j) pa[j] += b2f(hv[j]);
    }
  }
  #pragma unroll
  for (int j = 0; j < 8; ++j) red16[r][c * 8 + j] = pa[j];
  __syncthreads();
  if (t < 128){
    float ssum = 0.f;
    #pragma unroll
    for (int k = 0; k < 16; ++k) ssum += red16[k][t];
    pooled[(size_t)g * 384 + coloff + t] = ssum;
  }
}

// ---------------- layer-2 pool + classifier fused (block = graph) ----------
__global__ void k_poolclf(const unsigned short* __restrict__ h,
                          const int* __restrict__ gs,
                          const float* __restrict__ pooled,
                          const unsigned short* w1, const unsigned short* b1,
                          const unsigned short* w2, const unsigned short* b2c,
                          const unsigned short* gamma, const unsigned short* beta,
                          const unsigned short* mean, const unsigned short* var,
                          void* dout, const int* flag){
  __shared__ float red16[16][136];
  __shared__ float sg[384];
  __shared__ float st[256];
  __shared__ float red[256];
  int g = blockIdx.x;
  int t = threadIdx.x;
  int r = t >> 4;
  int c = t & 15;
  int s = gs[g];
  int e = gs[g + 1];
  float pa[8] = {0.f, 0.f, 0.f, 0.f, 0.f, 0.f, 0.f, 0.f};
  for (int n = s + r; n < e; n += 16){
    u16x8 hv = *(const u16x8*)(h + ((size_t)n << 7) + c * 8);
    #pragma unroll
    for (int j = 0; j < 8; ++j) pa[j] += b2f(hv[j]);
  }
  #pragma unroll
  for (int j = 0; j < 8; ++j) red16[r][c * 8 + j] = pa[j];
  sg[t] = pooled[(size_t)g * 384 + t];       // cols 0..255 from earlier pools
  __syncthreads();
  if (t < 128){
    float ssum = 0.f;
    #pragma unroll
    for (int k = 0; k < 16; ++k) ssum += red16[k][t];
    sg[256 + t] = ssum;                      // cols 256..383 local
  }
  __syncthreads();

  // classifier: z = relu(bn(g@W1+b1)) @ W2 + b2
  const unsigned short* wp = w1 + t;
  float acc = b2f(b1[t]);
  #pragma unroll 4
  for (int k = 0; k < 384; ++k) acc += sg[k] * b2f(wp[k * 256]);
  float zb = (acc - b2f(mean[t])) * rsqrtf(b2f(var[t]) + 1e-5f) * b2f(gamma[t]) + b2f(beta[t]);
  st[t] = fmaxf(zb, 0.f);
  __syncthreads();
  for (int cc = 0; cc < 2; ++cc){
    red[t] = st[t] * b2f(w2[t * 2 + cc]);
    __syncthreads();
    for (int ss = 128; ss > 0; ss >>= 1){
      if (t < ss) red[t] += red[t + ss];
      __syncthreads();
    }
    if (t == 0){
      float v = red[0] + b2f(b2c[cc]);
      if (*flag) ((unsigned short*)dout)[g * 2 + cc] = f2b(v);
      else       ((float*)dout)[g * 2 + cc] = v;
    }
    __syncthreads();
  }
}

extern "C" void kernel_launch(void* const* d_in, const int* in_sizes, int n_in,
                              void* d_out, int out_size, void* d_ws, size_t ws_size,
                              hipStream_t stream)
{
  const int* ei    = (const int*)d_in[1];
  const int* batch = (const int*)d_in[2];
  (void)n_in; (void)out_size; (void)ws_size;

  // flat layout, no overlays (ws >= 256 MiB per harness poison fills)
  char* w = (char*)d_ws;
  int* bcnt     = (int*)(w + 0);           //  2048 B
  int* bbase    = (int*)(w + 2048);        //  2048 B
  int* bcursor  = (int*)(w + 4096);        //  2048 B
  int* rowstart = (int*)(w + 6144);        //  400128 B -> 406272
  int* gstart   = (int*)(w + 406272);      //  4352 B -> 410624
  int* flag     = (int*)(w + 410624);      //  128 B -> 410752
  unsigned int* barr = (unsigned int*)(w + 410752);       // 6.4 MB -> 6810752
  int* csr      = (int*)(w + 6810752);     // 6.4 MB -> 13210752
  unsigned short* bufP = (unsigned short*)(w + 13210752); // 25.6 MB -> 38810752
  unsigned short* bufQ = (unsigned short*)(w + 38810752); // 25.6 MB -> 64410752
  unsigned short* pool = (unsigned short*)(w + 64410752); // 2 MB params -> 66410752
  unsigned char* t8    = (unsigned char*)(w + 66410752);  // 12.8 MB fp8 -> 79210752
  float* pooled = (float*)(w + 79210752);                 // 1.57 MB -> 80783616
  unsigned short* x8 = (unsigned short*)(w + 80783616);   // 1.6 MB -> 82383616

  static const int order[N_TENSORS] =
      {3, 4, 5, 6, 7, 8, 9, 10, 11, 12, 13, 14, 15, 16, 17, 18, 19, 20, 21, 22};
  CvtTable T;
  const unsigned short* pp[23];
  int off = 0;
  for (int j = 0; j < N_TENSORS; ++j){
    int i = order[j];
    T.d[j].src = d_in[i];
    T.d[j].n = in_sizes[i];
    T.d[j].off = off;
    pp[i] = pool + off;
    off += in_sizes[i];
  }
  T.total = off;

  const unsigned short* pw1[3] = {pp[3], pp[7],  pp[11]};
  const unsigned short* pb1[3] = {pp[4], pp[8],  pp[12]};
  const unsigned short* pw2[3] = {pp[5], pp[9],  pp[13]};
  const unsigned short* pb2[3] = {pp[6], pp[10], pp[14]};

  const int* src = ei;
  const int* dst = ei + N_EDGESC;
  int ntiles = (N_NODESC + 63) / 64;   // 1563
  int ncvt = (T.total + 255) / 256;
  int nc2 = 1 + (N_NODESC + 511) / 512;   // bscan block + gstart blocks

  // dtype detect + zero bcnt
  k_detect<<<dim3(1), dim3(256), 0, stream>>>((const unsigned short*)d_in[0], flag, bcnt);

  // bucketed CSR build (+ gstart, + param cvt, + x pad)
  k_bhist<<<dim3(256), dim3(256), 0, stream>>>(dst, bcnt);
  k_c2<<<dim3(nc2), dim3(512), 0, stream>>>(bcnt, bbase, bcursor, rowstart, batch, gstart);
  k_bscatter<<<dim3(256), dim3(256), 0, stream>>>(src, dst, bcursor, barr);
  k_c4<<<dim3(NB + ncvt + NPADB), dim3(256), 0, stream>>>(barr, bbase, rowstart, csr,
                                                          T, pool, flag, ncvt, d_in[0], x8);

  // layer 0: fused gather+matmul -> P; gemm W2 in-place; pool (+fp8 encode h0)
  k_l0<<<dim3((N_NODESC + 127) / 128), dim3(256), 0, stream>>>(x8, rowstart, csr, pw1[0], pb1[0], bufP);
  k_gemm128m<<<dim3(782), dim3(256), 0, stream>>>(bufP, pw2[0], pb2[0], bufP, ntiles);
  k_poolA<<<dim3(NUM_GRAPHSC), dim3(256), 0, stream>>>(bufP, gstart, pooled, 0, t8);

  // layer 1: fused agg+W1 (P,t8 -> Q = h1_1); gemm W2 in-place; pool (+fp8 t8)
  k_aggmm<<<dim3(ntiles), dim3(256), 0, stream>>>(bufP, t8, rowstart, csr,
                                                  pw1[1], pb1[1], bufQ);
  k_gemm128m<<<dim3(782), dim3(256), 0, stream>>>(bufQ, pw2[1], pb2[1], bufQ, ntiles);
  k_poolA<<<dim3(NUM_GRAPHSC), dim3(256), 0, stream>>>(bufQ, gstart, pooled, 128, t8);

  // layer 2: fused agg+W1 (Q,t8 -> P = h1_2); gemm W2 in-place; pool+classifier
  k_aggmm<<<dim3(ntiles), dim3(256), 0, stream>>>(bufQ, t8, rowstart, csr,
                                                  pw1[2], pb1[2], bufP);
  k_gemm128m<<<dim3(782), dim3(256), 0, stream>>>(bufP, pw2[2], pb2[2], bufP, ntiles);
  k_poolclf<<<dim3(NUM_GRAPHSC), dim3(256), 0, stream>>>(bufP, gstart, pooled,
                                                         pp[15], pp[16], pp[17], pp[18],
                                                         pp[19], pp[20], pp[21], pp[22],
                                                         d_out, flag);
}

// Round 11
// 368.378 us; speedup vs baseline: 1.2857x; 1.2857x over previous
//
// GINModel_15058155340592 — HIP implementation.
// Keep the identifier kernel symbol below: the harness uses it to map
// this source to its test (R1-R3 failed without it).
//
// JOURNAL (counter-driven):
//  R4: fused pool/fp8 into GEMM epilogue -> VGPR spill (WRITE 120MB, occ 13%).
//  R6: fused W1/W2 MLP kernel -> TWO weight sets co-resident -> 420MB scratch.
//      LESSON: one reg-resident weight set max (128 VGPR leaves no headroom).
//  R7: verified baseline 410 us (R2 structure + k_c4 padx fusion).
//  R8: pool vectorized + layer-2 pool+clf merged -> 398 us.
//  R9: GEMM B-frag column permutation -> 4x u16x8 epilogue stores -> 371 us.
//  R10: agg+W1 fusion -> NO spill (96 VGPR) but TLP collapse: 25000 -> 6252
//       waves on the latency-bound gather (occ 67%->17%, 1.2TB/s) -> 474 us.
//      LESSON: latency-bound gathers need max wave count; never tie their grid
//      to a GEMM tile structure. agg(x)GEMM fusion closed (R4/R6/R10 walls).
//  R11: revert to verified R9 config (370.8 us) — every kernel in it is
//       individually counter-validated.
#include <hip/hip_runtime.h>

#define N_NODESC    100000
#define N_EDGESC    1600000
#define NUM_GRAPHSC 1024
#define IN_FEATC    7
#define HDIM        128
#define N_TENSORS   20

// bucketed CSR build: bucket = dst >> 8 (256 nodes per bucket)
#define NB       391            // ceil(100000/256)
#define CHUNK_A  6250           // edges per block in bucket passes (256 blocks)
#define NPADB    391            // ceil(100000/256) padx blocks in k_c4 tail

typedef short s16x8 __attribute__((ext_vector_type(8)));
typedef float f32x4 __attribute__((ext_vector_type(4)));
typedef unsigned short u16x8 __attribute__((ext_vector_type(8)));

#if defined(__has_builtin)
# if __has_builtin(__builtin_amdgcn_cvt_pk_f32_fp8) && __has_builtin(__builtin_amdgcn_cvt_pk_fp8_f32)
#  define USE_HW_FP8 1
# endif
#endif

__global__ void GINModel_15058155340592_kernel(/* identifier-preserving stub */) {
}

__device__ __forceinline__ float b2f(unsigned short u){
  union { unsigned int i; float f; } v;
  v.i = ((unsigned int)u) << 16;
  return v.f;
}
__device__ __forceinline__ unsigned short f2b(float f){
  union { float f; unsigned int i; } v;
  v.f = f;
  unsigned int x = v.i;
  return (unsigned short)((x + 0x7fffu + ((x >> 16) & 1u)) >> 16);
}

// fp8 e4m3fn helpers (values are post-relu >= 0; stored as h/8, clamp 448)
__device__ __forceinline__ unsigned char enc_fp8(float h){
  float x = fminf(h * 0.125f, 448.f);
#ifdef USE_HW_FP8
  int r = __builtin_amdgcn_cvt_pk_fp8_f32(x, x, 0, false);
  return (unsigned char)(r & 0xFF);
#else
  union { float f; unsigned int i; } u; u.f = x;
  unsigned b = u.i;
  b += 0x7FFFF + ((b >> 20) & 1);           // RTNE to 3 mantissa bits
  int e = (int)((b >> 23) & 0xFF) - 120;    // e4m3 biased exponent
  unsigned m = (b >> 20) & 7;
  if (e <= 0) return 0;                     // flush subnormal
  if (e > 15) return 0x7E;                  // saturate 448
  return (unsigned char)((e << 3) | m);
#endif
}

// accumulate 4 fp8 bytes (packed in u) into a[base..base+3]
__device__ __forceinline__ void acc_fp8x4(unsigned int u, float* a){
#ifdef USE_HW_FP8
  auto lo = __builtin_amdgcn_cvt_pk_f32_fp8((int)u, false);
  auto hi = __builtin_amdgcn_cvt_pk_f32_fp8((int)u, true);
  a[0] += lo[0]; a[1] += lo[1]; a[2] += hi[0]; a[3] += hi[1];
#else
  #pragma unroll
  for (int k = 0; k < 4; ++k){
    unsigned b = (u >> (k * 8)) & 0xFF;
    unsigned e = (b >> 3) & 0xF;
    unsigned m = b & 7;
    union { unsigned int i; float f; } w;
    w.i = ((e + 120) << 23) | (m << 20);
    float v = (e == 0) ? (float)m * 0.001953125f : w.f;
    a[k] += v;
  }
#endif
}

// accumulate 4 bf16 (uint2) into 4 floats
__device__ __forceinline__ void acc_bf4(uint2 v, float& a0, float& a1,
                                        float& a2, float& a3){
  union { unsigned int i; float f; } t;
  t.i = v.x << 16;          a0 += t.f;
  t.i = v.x & 0xffff0000u;  a1 += t.f;
  t.i = v.y << 16;          a2 += t.f;
  t.i = v.y & 0xffff0000u;  a3 += t.f;
}

// ---------------- dtype detect (+ zero bcnt) ----------------
__global__ void k_detect(const unsigned short* xb, int* flag, int* bcnt){
  __shared__ int sh[256];
  int t = threadIdx.x;
  for (int i = t; i < 512; i += 256) bcnt[i] = 0;
  int cnt = 0;
  for (int i = t; i < 512; i += 256){
    unsigned e = (xb[i] >> 7) & 0xFF;
    if (e >= 0x68 && e <= 0x85) ++cnt;
  }
  sh[t] = cnt;
  __syncthreads();
  for (int s = 128; s > 0; s >>= 1){
    if (t < s) sh[t] += sh[t + s];
    __syncthreads();
  }
  if (t == 0) *flag = (sh[0] >= 400) ? 1 : 0;   // 1 = bf16 inputs, 0 = f32
}

struct CvtDesc { const void* src; int n; int off; };
struct CvtTable { CvtDesc d[N_TENSORS]; int total; };

// ---------------- bucketed CSR build ----------------
__global__ void k_bhist(const int* dst, int* bcnt){
  __shared__ int h[NB];
  int tid = threadIdx.x;
  for (int i = tid; i < NB; i += 256) h[i] = 0;
  __syncthreads();
  int beg = blockIdx.x * CHUNK_A;
  int end = beg + CHUNK_A < N_EDGESC ? beg + CHUNK_A : N_EDGESC;
  for (int e = beg + tid; e < end; e += 256)
    atomicAdd(&h[dst[e] >> 8], 1);
  __syncthreads();
  for (int i = tid; i < NB; i += 256)
    if (h[i]) atomicAdd(&bcnt[i], h[i]);
}

// block 0: scan bucket counts. blocks 1..: graph-start detection (gstart).
__global__ void k_c2(const int* bcnt, int* bbase, int* bcursor, int* rowstart,
                     const int* batch, int* gs){
  if (blockIdx.x == 0){
    __shared__ int sh[512];
    int t = threadIdx.x;
    int v = (t < NB) ? bcnt[t] : 0;
    sh[t] = v;
    __syncthreads();
    for (int off = 1; off < 512; off <<= 1){
      int a = (t >= off) ? sh[t - off] : 0;
      __syncthreads();
      sh[t] += a;
      __syncthreads();
    }
    int excl = sh[t] - v;
    if (t < NB){ bbase[t] = excl; bcursor[t] = excl; }
    if (t == NB) bbase[NB] = sh[t];    // == N_EDGESC
    if (t == 0) rowstart[N_NODESC] = N_EDGESC;
  } else {
    int n = (blockIdx.x - 1) * 512 + threadIdx.x;
    if (n >= N_NODESC) return;
    int b = batch[n];
    if (n == 0){
      for (int g = 0; g <= b; ++g) gs[g] = 0;
    } else {
      int pb = batch[n - 1];
      if (pb != b){
        for (int g = pb + 1; g <= b; ++g) gs[g] = n;
      }
    }
    if (n == N_NODESC - 1){
      for (int g = b + 1; g <= NUM_GRAPHSC; ++g) gs[g] = N_NODESC;
    }
  }
}

__global__ void k_bscatter(const int* src, const int* dst, int* bcursor,
                           unsigned int* barr){
  __shared__ int lhist[NB];
  __shared__ int lbase[NB];
  int tid = threadIdx.x;
  for (int i = tid; i < NB; i += 256) lhist[i] = 0;
  __syncthreads();
  int beg = blockIdx.x * CHUNK_A;
  int end = beg + CHUNK_A < N_EDGESC ? beg + CHUNK_A : N_EDGESC;
  for (int e = beg + tid; e < end; e += 256)
    atomicAdd(&lhist[dst[e] >> 8], 1);
  __syncthreads();
  for (int b = tid; b < NB; b += 256){
    int c = lhist[b];
    lbase[b] = c ? atomicAdd(&bcursor[b], c) : 0;
  }
  __syncthreads();
  for (int i = tid; i < NB; i += 256) lhist[i] = 0;   // reuse as run cursor
  __syncthreads();
  for (int e = beg + tid; e < end; e += 256){
    int d = dst[e];
    int b = d >> 8;
    int ofs = atomicAdd(&lhist[b], 1);
    barr[lbase[b] + ofs] = ((unsigned)(d & 255) << 17) | (unsigned)src[e];
  }
}

// blocks 0..NB-1: per-bucket CSR finalize (csr holds src<<7).
// blocks NB..NB+ncvtb-1: param pool conversion.
// blocks NB+ncvtb..: pad x into [N][8] bf16 rows (x8, 16 B/row, f7 = 0).
__global__ void k_c4(const unsigned int* barr, const int* bbase,
                     int* rowstart, int* csr,
                     CvtTable T, unsigned short* pool, const int* flag,
                     int ncvtb, const void* xin, unsigned short* x8){
  if (blockIdx.x < NB){
    __shared__ int h[256];
    __shared__ int sc[256];
    __shared__ int cur[256];
    int tid = threadIdx.x;
    int b = blockIdx.x;
    int beg = bbase[b];
    int end = bbase[b + 1];
    int n0 = b << 8;
    h[tid] = 0;
    __syncthreads();
    for (int i = beg + tid; i < end; i += 256)
      atomicAdd(&h[barr[i] >> 17], 1);
    __syncthreads();
    int v = h[tid];
    sc[tid] = v;
    __syncthreads();
    for (int off = 1; off < 256; off <<= 1){
      int a = (tid >= off) ? sc[tid - off] : 0;
      __syncthreads();
      sc[tid] += a;
      __syncthreads();
    }
    int excl = sc[tid] - v;
    int node = n0 + tid;
    if (node < N_NODESC) rowstart[node] = beg + excl;
    cur[tid] = beg + excl;
    __syncthreads();
    for (int i = beg + tid; i < end; i += 256){
      unsigned int e = barr[i];
      int local = e >> 17;
      int slot = atomicAdd(&cur[local], 1);
      csr[slot] = (int)(e & 0x1FFFF) << 7;
    }
  } else {
    int bx = blockIdx.x - NB;
    if (bx < ncvtb){
      int i = bx * 256 + threadIdx.x;
      if (i >= T.total) return;
      int isbf = *flag;
      for (int j = 0; j < N_TENSORS; ++j){
        int o = T.d[j].off;
        if (i >= o && i < o + T.d[j].n){
          int k = i - o;
          if (isbf) pool[i] = ((const unsigned short*)T.d[j].src)[k];
          else      pool[i] = f2b(((const float*)T.d[j].src)[k]);
          return;
        }
      }
    } else {
      int n = (bx - ncvtb) * 256 + threadIdx.x;
      if (n >= N_NODESC) return;
      u16x8 o;
      if (*flag){
        const unsigned short* s = (const unsigned short*)xin + (size_t)n * IN_FEATC;
        #pragma unroll
        for (int j = 0; j < IN_FEATC; ++j) o[j] = s[j];
      } else {
        const float* s = (const float*)xin + (size_t)n * IN_FEATC;
        #pragma unroll
        for (int j = 0; j < IN_FEATC; ++j) o[j] = f2b(s[j]);
      }
      o[7] = 0;
      *(u16x8*)(x8 + (size_t)n * 8) = o;
    }
  }
}

// ---------------- layer 0: fused aggregate + [7]->[128] matmul ----------------
// 2 lanes per node (32 nodes/wave, 128 nodes/block). Each lane privately
// accumulates its 8-B half of the padded 16-B x8 row per edge (uint2 gather,
// 4-deep unrolled). z staged via 4 KB LDS; matmul keeps the 7x2 weight slice
// in registers; stores write coalesced 256-B rows.
__global__ __launch_bounds__(256)
void k_l0(const unsigned short* x8, const int* rs, const int* csr,
          const unsigned short* w1, const unsigned short* b1,
          unsigned short* t){
  __shared__ __align__(16) float sz[128 * 8];
  int tid  = threadIdx.x;
  int lane = tid & 63;
  int wave = tid >> 6;
  int p    = tid & 1;            // half-row selector (f0-3 / f4-7)
  int bn   = tid >> 1;           // node slot in block 0..127
  int n    = blockIdx.x * 128 + bn;

  // per-lane weight slice: cols c0, c0+1 for k = 0..6 (+ bias pair)
  int c0 = lane * 2;
  float wa[IN_FEATC], wb[IN_FEATC];
  #pragma unroll
  for (int k = 0; k < IN_FEATC; ++k){
    unsigned int u = *(const unsigned int*)(w1 + k * HDIM + c0);
    union { unsigned int i; float f; } lo, hi;
    lo.i = u << 16; hi.i = u & 0xffff0000u;
    wa[k] = lo.f; wb[k] = hi.f;
  }
  unsigned int ub = *(const unsigned int*)(b1 + c0);
  union { unsigned int i; float f; } blo, bhi;
  blo.i = ub << 16; bhi.i = ub & 0xffff0000u;
  float bv0 = blo.f, bv1 = bhi.f;

  // aggregation: gather neighbor half-rows (csr holds src<<7 -> byte off = csr>>3)
  float a0 = 0.f, a1 = 0.f, a2 = 0.f, a3 = 0.f;
  int beg = 0, end = 0;
  if (n < N_NODESC){ beg = rs[n]; end = rs[n + 1]; }
  const unsigned char* xb = (const unsigned char*)x8 + p * 8;
  int i = beg;
  for (; i + 4 <= end; i += 4){
    int o0 = csr[i + 0];
    int o1 = csr[i + 1];
    int o2 = csr[i + 2];
    int o3 = csr[i + 3];
    uint2 v0 = *(const uint2*)(xb + (o0 >> 3));
    uint2 v1 = *(const uint2*)(xb + (o1 >> 3));
    uint2 v2 = *(const uint2*)(xb + (o2 >> 3));
    uint2 v3 = *(const uint2*)(xb + (o3 >> 3));
    acc_bf4(v0, a0, a1, a2, a3);
    acc_bf4(v1, a0, a1, a2, a3);
    acc_bf4(v2, a0, a1, a2, a3);
    acc_bf4(v3, a0, a1, a2, a3);
  }
  for (; i < end; ++i){
    uint2 v = *(const uint2*)(xb + (csr[i] >> 3));
    acc_bf4(v, a0, a1, a2, a3);
  }
  if (n < N_NODESC){  // self term (eps=0)
    uint2 v = *(const uint2*)((const unsigned char*)x8 + (size_t)n * 16 + p * 8);
    acc_bf4(v, a0, a1, a2, a3);
  }
  *(f32x4*)&sz[bn * 8 + p * 4] = f32x4{a0, a1, a2, a3};
  __syncthreads();

  // matmul: wave iterates its 32 nodes; z broadcast from LDS, weights in regs
  int j0 = wave * 32;
  for (int j = 0; j < 32; ++j){
    int no = blockIdx.x * 128 + j0 + j;
    f32x4 z0 = *(const f32x4*)&sz[(j0 + j) * 8];
    f32x4 z1 = *(const f32x4*)&sz[(j0 + j) * 8 + 4];
    float acc0 = bv0, acc1 = bv1;
    acc0 += z0[0] * wa[0]; acc1 += z0[0] * wb[0];
    acc0 += z0[1] * wa[1]; acc1 += z0[1] * wb[1];
    acc0 += z0[2] * wa[2]; acc1 += z0[2] * wb[2];
    acc0 += z0[3] * wa[3]; acc1 += z0[3] * wb[3];
    acc0 += z1[0] * wa[4]; acc1 += z1[0] * wb[4];
    acc0 += z1[1] * wa[5]; acc1 += z1[1] * wb[5];
    acc0 += z1[2] * wa[6]; acc1 += z1[2] * wb[6];
    if (no < N_NODESC){
      unsigned int pk = ((unsigned)f2b(fmaxf(acc1, 0.f)) << 16)
                      | (unsigned)f2b(fmaxf(acc0, 0.f));
      *(unsigned int*)(t + ((size_t)no << 7) + c0) = pk;
    }
  }
}

// ---------------- MFMA GEMM: [N,128]@[128,128]+bias, relu, bf16 ----------------
// R9 column-permuted B-fragments; coalesced u16x8 epilogue.
__global__ __launch_bounds__(256, 2)
void k_gemm128m(const unsigned short* A, const unsigned short* W,
                const unsigned short* bias, unsigned short* C, int ntiles)
{
  int wave = threadIdx.x >> 6;
  int lane = threadIdx.x & 63;
  int quad = lane >> 4;
  int l16  = lane & 15;

  union BU { s16x8 v; unsigned short s[8]; };
  BU bf[4][8];
  #pragma unroll
  for (int ks = 0; ks < 4; ++ks)
    #pragma unroll
    for (int ct = 0; ct < 8; ++ct){
      int c = l16 * 8 + ct;               // permuted column assignment
      #pragma unroll
      for (int j = 0; j < 8; ++j)
        bf[ks][ct].s[j] = W[(ks * 32 + quad * 8 + j) * HDIM + c];
    }

  float bv[8];
  #pragma unroll
  for (int ct = 0; ct < 8; ++ct) bv[ct] = b2f(bias[l16 * 8 + ct]);

  for (int tile = blockIdx.x; tile < ntiles; tile += gridDim.x){
    int r = tile * 64 + wave * 16 + l16;
    BU af[4];
    if (r < N_NODESC){
      const unsigned short* arow = A + (size_t)r * HDIM;
      #pragma unroll
      for (int ks = 0; ks < 4; ++ks)
        af[ks].v = *reinterpret_cast<const s16x8*>(arow + ks * 32 + quad * 8);
    } else {
      #pragma unroll
      for (int ks = 0; ks < 4; ++ks)
        #pragma unroll
        for (int j = 0; j < 8; ++j) af[ks].s[j] = 0;
    }
    f32x4 acc[8];
    #pragma unroll
    for (int ct = 0; ct < 8; ++ct) acc[ct] = f32x4{0.f, 0.f, 0.f, 0.f};
    #pragma unroll
    for (int ks = 0; ks < 4; ++ks)
      #pragma unroll
      for (int ct = 0; ct < 8; ++ct)
        acc[ct] = __builtin_amdgcn_mfma_f32_16x16x32_bf16(af[ks].v, bf[ks][ct].v,
                                                          acc[ct], 0, 0, 0);

    int orow = tile * 64 + wave * 16 + quad * 4;  // C/D row = quad*4 + reg
    #pragma unroll
    for (int rr = 0; rr < 4; ++rr){
      int row = orow + rr;
      if (row < N_NODESC){
        u16x8 o;
        #pragma unroll
        for (int ct = 0; ct < 8; ++ct)
          o[ct] = f2b(fmaxf(acc[ct][rr] + bv[ct], 0.f));
        *(u16x8*)(C + ((size_t)row << 7) + l16 * 8) = o;
      }
    }
  }
}

// ---------------- CSR aggregate (fp8 gather table + bf16 self) ----------------
// One 16-lane slot per node (4 nodes/wave, 16 nodes/block). Each slot privately
// accumulates its node's full 128-feature row across its edge list.
__global__ void k_agg128(const unsigned short* hin, const unsigned char* t8,
                         const int* rs, const int* csr, unsigned short* zout){
  int lane = threadIdx.x & 63;
  int slot = lane >> 4;        // which of this wave's 4 nodes
  int fl   = lane & 15;        // feature chunk 0..15 (8 fp8 values each)
  int n = blockIdx.x * 16 + (threadIdx.x >> 6) * 4 + slot;
  const unsigned char* hb8 = t8 + fl * 8;   // lane's 8-B sub-row offset
  int beg = rs[n];
  int end = rs[n + 1];
  float a[8] = {0.f, 0.f, 0.f, 0.f, 0.f, 0.f, 0.f, 0.f};
  int i = beg;
  for (; i + 4 <= end; i += 4){
    int o0 = csr[i + 0];
    int o1 = csr[i + 1];
    int o2 = csr[i + 2];
    int o3 = csr[i + 3];
    uint2 v0 = *(const uint2*)(hb8 + o0);
    uint2 v1 = *(const uint2*)(hb8 + o1);
    uint2 v2 = *(const uint2*)(hb8 + o2);
    uint2 v3 = *(const uint2*)(hb8 + o3);
    acc_fp8x4(v0.x, a); acc_fp8x4(v0.y, a + 4);
    acc_fp8x4(v1.x, a); acc_fp8x4(v1.y, a + 4);
    acc_fp8x4(v2.x, a); acc_fp8x4(v2.y, a + 4);
    acc_fp8x4(v3.x, a); acc_fp8x4(v3.y, a + 4);
  }
  for (; i < end; ++i){
    int o = csr[i];
    uint2 v = *(const uint2*)(hb8 + o);
    acc_fp8x4(v.x, a); acc_fp8x4(v.y, a + 4);
  }
  // self term (eps=0) in bf16, undo h/8 storage scale, pack out
  u16x8 vs = *(const u16x8*)(hin + ((size_t)n << 7) + fl * 8);
  u16x8 o;
  #pragma unroll
  for (int j = 0; j < 8; ++j) o[j] = f2b(a[j] * 8.f + b2f(vs[j]));
  *(u16x8*)(zout + ((size_t)n << 7) + fl * 8) = o;
}

// ---------------- pooling v2: u16x8 loads, packed fp8, LDS reduce -----------
__global__ void k_poolA(const unsigned short* __restrict__ h,
                        const int* __restrict__ gs,
                        float* __restrict__ pooled, int coloff,
                        unsigned char* __restrict__ c8){
  __shared__ float red16[16][136];
  int g = blockIdx.x;
  int t = threadIdx.x;
  int r = t >> 4;
  int c = t & 15;
  int s = gs[g];
  int e = gs[g + 1];
  float pa[8] = {0.f, 0.f, 0.f, 0.f, 0.f, 0.f, 0.f, 0.f};
  if (c8){
    for (int n = s + r; n < e; n += 16){
      u16x8 hv = *(const u16x8*)(h + ((size_t)n << 7) + c * 8);
      unsigned int w0 = (unsigned)enc_fp8(b2f(hv[0]))
                      | ((unsigned)enc_fp8(b2f(hv[1])) << 8)
                      | ((unsigned)enc_fp8(b2f(hv[2])) << 16)
                      | ((unsigned)enc_fp8(b2f(hv[3])) << 24);
      unsigned int w1 = (unsigned)enc_fp8(b2f(hv[4]))
                      | ((unsigned)enc_fp8(b2f(hv[5])) << 8)
                      | ((unsigned)enc_fp8(b2f(hv[6])) << 16)
                      | ((unsigned)enc_fp8(b2f(hv[7])) << 24);
      *(uint2*)(c8 + ((size_t)n << 7) + c * 8) = uint2{w0, w1};
      #pragma unroll
      for (int j = 0; j < 8; ++j) pa[j] += b2f(hv[j]);
    }
  } else {
    for (int n = s + r; n < e; n += 16){
      u16x8 hv = *(const u16x8*)(h + ((size_t)n << 7) + c * 8);
      #pragma unroll
      for (int j = 0; j < 8; ++j) pa[j] += b2f(hv[j]);
    }
  }
  #pragma unroll
  for (int j = 0; j < 8; ++j) red16[r][c * 8 + j] = pa[j];
  __syncthreads();
  if (t < 128){
    float ssum = 0.f;
    #pragma unroll
    for (int k = 0; k < 16; ++k) ssum += red16[k][t];
    pooled[(size_t)g * 384 + coloff + t] = ssum;
  }
}

// ---------------- layer-2 pool + classifier fused (block = graph) ----------
__global__ void k_poolclf(const unsigned short* __restrict__ h,
                          const int* __restrict__ gs,
                          const float* __restrict__ pooled,
                          const unsigned short* w1, const unsigned short* b1,
                          const unsigned short* w2, const unsigned short* b2c,
                          const unsigned short* gamma, const unsigned short* beta,
                          const unsigned short* mean, const unsigned short* var,
                          void* dout, const int* flag){
  __shared__ float red16[16][136];
  __shared__ float sg[384];
  __shared__ float st[256];
  __shared__ float red[256];
  int g = blockIdx.x;
  int t = threadIdx.x;
  int r = t >> 4;
  int c = t & 15;
  int s = gs[g];
  int e = gs[g + 1];
  float pa[8] = {0.f, 0.f, 0.f, 0.f, 0.f, 0.f, 0.f, 0.f};
  for (int n = s + r; n < e; n += 16){
    u16x8 hv = *(const u16x8*)(h + ((size_t)n << 7) + c * 8);
    #pragma unroll
    for (int j = 0; j < 8; ++j) pa[j] += b2f(hv[j]);
  }
  #pragma unroll
  for (int j = 0; j < 8; ++j) red16[r][c * 8 + j] = pa[j];
  sg[t] = pooled[(size_t)g * 384 + t];       // cols 0..255 from earlier pools
  __syncthreads();
  if (t < 128){
    float ssum = 0.f;
    #pragma unroll
    for (int k = 0; k < 16; ++k) ssum += red16[k][t];
    sg[256 + t] = ssum;                      // cols 256..383 local
  }
  __syncthreads();

  // classifier: z = relu(bn(g@W1+b1)) @ W2 + b2
  const unsigned short* wp = w1 + t;
  float acc = b2f(b1[t]);
  #pragma unroll 4
  for (int k = 0; k < 384; ++k) acc += sg[k] * b2f(wp[k * 256]);
  float zb = (acc - b2f(mean[t])) * rsqrtf(b2f(var[t]) + 1e-5f) * b2f(gamma[t]) + b2f(beta[t]);
  st[t] = fmaxf(zb, 0.f);
  __syncthreads();
  for (int cc = 0; cc < 2; ++cc){
    red[t] = st[t] * b2f(w2[t * 2 + cc]);
    __syncthreads();
    for (int ss = 128; ss > 0; ss >>= 1){
      if (t < ss) red[t] += red[t + ss];
      __syncthreads();
    }
    if (t == 0){
      float v = red[0] + b2f(b2c[cc]);
      if (*flag) ((unsigned short*)dout)[g * 2 + cc] = f2b(v);
      else       ((float*)dout)[g * 2 + cc] = v;
    }
    __syncthreads();
  }
}

extern "C" void kernel_launch(void* const* d_in, const int* in_sizes, int n_in,
                              void* d_out, int out_size, void* d_ws, size_t ws_size,
                              hipStream_t stream)
{
  const int* ei    = (const int*)d_in[1];
  const int* batch = (const int*)d_in[2];
  (void)n_in; (void)out_size; (void)ws_size;

  // flat layout, no overlays (ws >= 256 MiB per harness poison fills)
  char* w = (char*)d_ws;
  int* bcnt     = (int*)(w + 0);           //  2048 B
  int* bbase    = (int*)(w + 2048);        //  2048 B
  int* bcursor  = (int*)(w + 4096);        //  2048 B
  int* rowstart = (int*)(w + 6144);        //  400128 B -> 406272
  int* gstart   = (int*)(w + 406272);      //  4352 B -> 410624
  int* flag     = (int*)(w + 410624);      //  128 B -> 410752
  unsigned int* barr = (unsigned int*)(w + 410752);       // 6.4 MB -> 6810752
  int* csr      = (int*)(w + 6810752);     // 6.4 MB -> 13210752
  unsigned short* bufP = (unsigned short*)(w + 13210752); // 25.6 MB -> 38810752
  unsigned short* bufQ = (unsigned short*)(w + 38810752); // 25.6 MB -> 64410752
  unsigned short* pool = (unsigned short*)(w + 64410752); // 2 MB params -> 66410752
  unsigned char* t8    = (unsigned char*)(w + 66410752);  // 12.8 MB fp8 -> 79210752
  float* pooled = (float*)(w + 79210752);                 // 1.57 MB -> 80783616
  unsigned short* x8 = (unsigned short*)(w + 80783616);   // 1.6 MB -> 82383616

  static const int order[N_TENSORS] =
      {3, 4, 5, 6, 7, 8, 9, 10, 11, 12, 13, 14, 15, 16, 17, 18, 19, 20, 21, 22};
  CvtTable T;
  const unsigned short* pp[23];
  int off = 0;
  for (int j = 0; j < N_TENSORS; ++j){
    int i = order[j];
    T.d[j].src = d_in[i];
    T.d[j].n = in_sizes[i];
    T.d[j].off = off;
    pp[i] = pool + off;
    off += in_sizes[i];
  }
  T.total = off;

  const unsigned short* pw1[3] = {pp[3], pp[7],  pp[11]};
  const unsigned short* pb1[3] = {pp[4], pp[8],  pp[12]};
  const unsigned short* pw2[3] = {pp[5], pp[9],  pp[13]};
  const unsigned short* pb2[3] = {pp[6], pp[10], pp[14]};

  const int* src = ei;
  const int* dst = ei + N_EDGESC;
  int ntiles = (N_NODESC + 63) / 64;   // 1563
  int ncvt = (T.total + 255) / 256;
  int nc2 = 1 + (N_NODESC + 511) / 512;   // bscan block + gstart blocks

  // dtype detect + zero bcnt
  k_detect<<<dim3(1), dim3(256), 0, stream>>>((const unsigned short*)d_in[0], flag, bcnt);

  // bucketed CSR build (+ gstart, + param cvt, + x pad)
  k_bhist<<<dim3(256), dim3(256), 0, stream>>>(dst, bcnt);
  k_c2<<<dim3(nc2), dim3(512), 0, stream>>>(bcnt, bbase, bcursor, rowstart, batch, gstart);
  k_bscatter<<<dim3(256), dim3(256), 0, stream>>>(src, dst, bcursor, barr);
  k_c4<<<dim3(NB + ncvt + NPADB), dim3(256), 0, stream>>>(barr, bbase, rowstart, csr,
                                                          T, pool, flag, ncvt, d_in[0], x8);

  // layer 0: fused gather+matmul -> P; gemm W2 in-place; pool (+fp8 encode h1)
  k_l0<<<dim3((N_NODESC + 127) / 128), dim3(256), 0, stream>>>(x8, rowstart, csr, pw1[0], pb1[0], bufP);
  k_gemm128m<<<dim3(782), dim3(256), 0, stream>>>(bufP, pw2[0], pb2[0], bufP, ntiles);
  k_poolA<<<dim3(NUM_GRAPHSC), dim3(256), 0, stream>>>(bufP, gstart, pooled, 0, t8);

  // layer 1: P -> Q (fp8 gather); gemm W1; gemm W2 (in-place); pool (+fp8 t8)
  k_agg128<<<dim3(N_NODESC / 16), dim3(256), 0, stream>>>(bufP, t8, rowstart, csr, bufQ);
  k_gemm128m<<<dim3(782), dim3(256), 0, stream>>>(bufQ, pw1[1], pb1[1], bufQ, ntiles);
  k_gemm128m<<<dim3(782), dim3(256), 0, stream>>>(bufQ, pw2[1], pb2[1], bufQ, ntiles);
  k_poolA<<<dim3(NUM_GRAPHSC), dim3(256), 0, stream>>>(bufQ, gstart, pooled, 128, t8);

  // layer 2: Q -> P (fp8 gather); gemm W1; gemm W2 (in-place); pool+classifier
  k_agg128<<<dim3(N_NODESC / 16), dim3(256), 0, stream>>>(bufQ, t8, rowstart, csr, bufP);
  k_gemm128m<<<dim3(782), dim3(256), 0, stream>>>(bufP, pw1[2], pb1[2], bufP, ntiles);
  k_gemm128m<<<dim3(782), dim3(256), 0, stream>>>(bufP, pw2[2], pb2[2], bufP, ntiles);
  k_poolclf<<<dim3(NUM_GRAPHSC), dim3(256), 0, stream>>>(bufP, gstart, pooled,
                                                         pp[15], pp[16], pp[17], pp[18],
                                                         pp[19], pp[20], pp[21], pp[22],
                                                         d_out, flag);
}